// Round 1
// baseline (190.177 us; speedup 1.0000x reference)
//
#include <hip/hip_runtime.h>

// BiliSample fused: bilinear-sample BEV features + 1x1 conv (GEMM) + bias.
//   img_feat: (2, 64, 32, 64) f32   pix_T_cam: (2,3,3) f32
//   conv_w:   (128, 512) f32        conv_b: (128,) f32
//   out:      (2, 128, 200, 200) f32, flat idx = (b*128+o)*40000 + z*200 + x
// n = z*200 + x in [0,40000); k = c*8 + y in [0,512).
// Grid: (625 n-tiles of 64, 2 batches). Block: 256 threads.

#define NPOS 40000

__global__ __launch_bounds__(256, 2)
void bili_fused(const float* __restrict__ img,
                const float* __restrict__ pixT,
                const float* __restrict__ convw,
                const float* __restrict__ convb,
                float* __restrict__ out)
{
    // F tile: 64 n-rows x 64 chunks; chunk c (16B) = 8 bf16 samples (y=0..7) for channel c.
    // XOR swizzle on chunk index with ((n>>2)&7): write instrs and read instrs both <=2-way.
    __shared__ uint4 Fs[64 * 64];   // 64 KiB

    const int t  = threadIdx.x;
    const int b  = blockIdx.y;
    const int n0 = blockIdx.x * 64;

    // ---------------- stage 1: sample into LDS (bf16) ----------------
    {
        const int nloc = t & 63;
        const int kseg = t >> 6;          // 4 threads share one n, split channels
        const int n = n0 + nloc;
        const int z = n / 200;
        const int x = n - z * 200;

        const float pxv = (x * (1.0f/199.0f) - 0.5f) * 80.0f;
        const float pzv = (z * (1.0f/199.0f)) * 80.0f;

        const float* Kb = pixT + b * 9;
        const float K00 = Kb[0], K01 = Kb[1], K02 = Kb[2];
        const float K10 = Kb[3], K11 = Kb[4], K12 = Kb[5];
        const float K20 = Kb[6], K21 = Kb[7], K22 = Kb[8];

        int   xi0a[8], xi1a[8], yi0a[8], yi1a[8];
        float wx0a[8], wx1a[8], wy0a[8], wy1a[8];

        #pragma unroll
        for (int y = 0; y < 8; ++y) {
            const float pyv = (y * (1.0f/7.0f) - 0.5f) * 6.0f;
            const float p0 = K00*pxv + K01*pyv + K02*pzv;
            const float p1 = K10*pxv + K11*pyv + K12*pzv;
            const float d  = K20*pxv + K21*pyv + K22*pzv;
            const float dpe = d + 1e-8f;
            const float u01 = p0 / dpe / 512.0f;
            const float v01 = p1 / dpe / 256.0f;
            const float vf = (u01 >= 0.0f && u01 <= 1.0f &&
                              v01 >= 0.0f && v01 <= 1.0f) ? 1.0f : 0.0f;

            float xp = u01 * 64.0f - 0.5f;
            xp = fminf(fmaxf(xp, -2.0f), 66.0f);     // safe int cast; exact for valid pts
            const float x0f = floorf(xp);
            const float wx = xp - x0f;
            const int x0 = (int)x0f, x1i = x0 + 1;
            wx0a[y] = (1.0f - wx) * vf * ((x0  >= 0 && x0  < 64) ? 1.0f : 0.0f);
            wx1a[y] = wx          * vf * ((x1i >= 0 && x1i < 64) ? 1.0f : 0.0f);
            xi0a[y] = min(max(x0, 0), 63);
            xi1a[y] = min(max(x1i, 0), 63);

            float yp = v01 * 32.0f - 0.5f;
            yp = fminf(fmaxf(yp, -2.0f), 34.0f);
            const float y0f = floorf(yp);
            const float wy = yp - y0f;
            const int y0 = (int)y0f, y1i = y0 + 1;
            wy0a[y] = (1.0f - wy) * ((y0  >= 0 && y0  < 32) ? 1.0f : 0.0f);
            wy1a[y] = wy          * ((y1i >= 0 && y1i < 32) ? 1.0f : 0.0f);
            yi0a[y] = min(max(y0, 0), 31);
            yi1a[y] = min(max(y1i, 0), 31);
        }

        const float* imgb = img + b * (64*32*64);
        const int swz = (nloc >> 2) & 7;
        #pragma unroll 1
        for (int ci = 0; ci < 16; ++ci) {
            const int c = (kseg << 4) + ci;
            const float* pc = imgb + (c << 11);      // c * 32*64
            unsigned int tmp[4];
            #pragma unroll
            for (int y = 0; y < 8; ++y) {
                const float* r0 = pc + (yi0a[y] << 6);
                const float* r1 = pc + (yi1a[y] << 6);
                const float h0 = wx0a[y]*r0[xi0a[y]] + wx1a[y]*r0[xi1a[y]];
                const float h1 = wx0a[y]*r1[xi0a[y]] + wx1a[y]*r1[xi1a[y]];
                const float h  = wy0a[y]*h0 + wy1a[y]*h1;
                unsigned int u = __float_as_uint(h);
                u = (u + 0x7fffu + ((u >> 16) & 1u)) >> 16;   // f32 -> bf16 RNE
                if ((y & 1) == 0) tmp[y >> 1] = u;
                else              tmp[y >> 1] |= (u << 16);
            }
            Fs[(nloc << 6) + (c ^ swz)] = make_uint4(tmp[0], tmp[1], tmp[2], tmp[3]);
        }
    }

    __syncthreads();

    // ---------------- stage 2: out[o,n] = sum_k W[o,k]*F[n,k] + bias[o] ----------------
    {
        const int og = t >> 4;          // 0..15 -> o = og*8
        const int xg = t & 15;          // 0..15 -> n_local = xg*4
        const int obase = og << 3;
        const int nb = xg << 2;
        const int swz = xg & 7;         // == ((nb+j)>>2)&7 for j in 0..3

        float acc[8][4];
        #pragma unroll
        for (int i = 0; i < 8; ++i) {
            const float bv = convb[obase + i];
            #pragma unroll
            for (int j = 0; j < 4; ++j) acc[i][j] = bv;
        }

        const float4* wp = (const float4*)convw;    // [128][128] float4 view

        #pragma unroll 2
        for (int k8 = 0; k8 < 64; ++k8) {
            float f[4][8];
            #pragma unroll
            for (int j = 0; j < 4; ++j) {
                const uint4 v = Fs[((nb + j) << 6) + (k8 ^ swz)];
                f[j][0] = __uint_as_float(v.x << 16);
                f[j][1] = __uint_as_float(v.x & 0xffff0000u);
                f[j][2] = __uint_as_float(v.y << 16);
                f[j][3] = __uint_as_float(v.y & 0xffff0000u);
                f[j][4] = __uint_as_float(v.z << 16);
                f[j][5] = __uint_as_float(v.z & 0xffff0000u);
                f[j][6] = __uint_as_float(v.w << 16);
                f[j][7] = __uint_as_float(v.w & 0xffff0000u);
            }
            #pragma unroll
            for (int i = 0; i < 8; ++i) {
                const float4 w0 = wp[(obase + i) * 128 + k8*2];
                const float4 w1 = wp[(obase + i) * 128 + k8*2 + 1];
                #pragma unroll
                for (int j = 0; j < 4; ++j) {
                    acc[i][j] += w0.x * f[j][0];
                    acc[i][j] += w0.y * f[j][1];
                    acc[i][j] += w0.z * f[j][2];
                    acc[i][j] += w0.w * f[j][3];
                    acc[i][j] += w1.x * f[j][4];
                    acc[i][j] += w1.y * f[j][5];
                    acc[i][j] += w1.z * f[j][6];
                    acc[i][j] += w1.w * f[j][7];
                }
            }
        }

        float* op = out + (b * 128 + obase) * NPOS + n0 + nb;
        #pragma unroll
        for (int i = 0; i < 8; ++i) {
            float4 v;
            v.x = acc[i][0]; v.y = acc[i][1]; v.z = acc[i][2]; v.w = acc[i][3];
            *(float4*)(op + i * NPOS) = v;
        }
    }
}

extern "C" void kernel_launch(void* const* d_in, const int* in_sizes, int n_in,
                              void* d_out, int out_size, void* d_ws, size_t ws_size,
                              hipStream_t stream) {
    const float* img   = (const float*)d_in[0];
    const float* pixT  = (const float*)d_in[1];
    const float* convw = (const float*)d_in[2];
    const float* convb = (const float*)d_in[3];
    float* out = (float*)d_out;

    dim3 grid(625, 2, 1);
    dim3 block(256, 1, 1);
    hipLaunchKernelGGL(bili_fused, grid, block, 0, stream,
                       img, pixT, convw, convb, out);
}

// Round 2
// 48.949 us; speedup vs baseline: 3.8852x; 3.8852x over previous
//
#include <hip/hip_runtime.h>

// BiliSample fused: bilinear-sample BEV features + 1x1 conv (GEMM) + bias.
// img_feat (2,64,32,64) f32, pix_T_cam (2,3,3) f32, conv_w (128,512) f32,
// conv_b (128,) f32 -> out (2,128,200,200) f32.
//
// Plan:
//  prep kernel:  imgT[b][y][x][c] = bf16(img[b][c][y][x])   (c contiguous!)
//                Wp[o][k'=y*64+c] = bf16(conv_w[o][c*8+y])  (k-permuted)
//  main kernel:  per block (64 n-positions, one batch):
//    phase A: 512 (n,y) projections -> 4 corner offsets + 4 weights in LDS
//    phase B: 8-lane groups sample 64 channels/corner via uint4 loads,
//             accumulate f32, pack bf16, write F[64][512] LDS (XOR-swizzled)
//    phase C: 4 waves x (2 o-tiles x 4 n-tiles) mfma_f32_16x16x32_bf16,
//             A-fragments straight from global Wp (L2-resident).

#define NPOS 40000

typedef short bf16x8 __attribute__((ext_vector_type(8)));
typedef float f32x4  __attribute__((ext_vector_type(4)));

__device__ __forceinline__ unsigned rne16(float f) {
    unsigned u = __float_as_uint(f);
    return (u + 0x7fffu + ((u >> 16) & 1u)) >> 16;
}
__device__ __forceinline__ float lo16(unsigned u) { return __uint_as_float(u << 16); }
__device__ __forceinline__ float hi16(unsigned u) { return __uint_as_float(u & 0xffff0000u); }

// ---------------- prep: transpose img to channel-major bf16, permute W ----------------
__global__ __launch_bounds__(256)
void bili_prep(const float* __restrict__ img, const float* __restrict__ convw,
               unsigned short* __restrict__ imgT, unsigned short* __restrict__ Wp)
{
    const int i = blockIdx.x * 256 + threadIdx.x;
    if (blockIdx.x < 1024) {
        // imgT[b][y][x][c], i = ((b*32+y)*64+x)*64+c
        const int c = i & 63, x = (i >> 6) & 63, y = (i >> 12) & 31, b = i >> 17;
        imgT[i] = (unsigned short)rne16(img[((b * 64 + c) * 32 + y) * 64 + x]);
    } else {
        const int j = i - 1024 * 256;            // 0..65535
        const int k = j & 511, o = j >> 9;
        const int y = k >> 6, c = k & 63;
        Wp[j] = (unsigned short)rne16(convw[o * 512 + c * 8 + y]);
    }
}

// ---------------- main fused kernel ----------------
__global__ __launch_bounds__(256, 2)
void bili_main(const uint4* __restrict__ imgTq,     // per-batch stride 16384 uint4
               const unsigned short* __restrict__ Wp,
               const float* __restrict__ pixT,
               const float* __restrict__ convb,
               float* __restrict__ out)
{
    __shared__ uint4  FsU[4096];    // F[64 n][512 k'] bf16, 64 KiB, col-XOR swizzled
    __shared__ int4   offsL[512];   // per (n,y): 4 corner uint4-offsets into imgT batch
    __shared__ float4 wtsL[512];    // per (n,y): 4 corner weights

    const int t  = threadIdx.x;
    const int b  = blockIdx.y;
    const int n0 = blockIdx.x * 64;

    // ---------- phase A: projections ----------
    {
        const float* Kb = pixT + b * 9;
        const float K00 = Kb[0], K01 = Kb[1], K02 = Kb[2];
        const float K10 = Kb[3], K11 = Kb[4], K12 = Kb[5];
        const float K20 = Kb[6], K21 = Kb[7], K22 = Kb[8];

        #pragma unroll
        for (int r = 0; r < 2; ++r) {
            const int p    = r * 256 + t;        // 0..511
            const int nloc = p >> 3;
            const int y    = p & 7;
            const int n = n0 + nloc;
            const int z = n / 200;
            const int x = n - z * 200;

            const float pxv = (x * (1.0f / 199.0f) - 0.5f) * 80.0f;
            const float pzv = (z * (1.0f / 199.0f)) * 80.0f;
            const float pyv = (y * (1.0f / 7.0f) - 0.5f) * 6.0f;

            const float p0 = K00 * pxv + K01 * pyv + K02 * pzv;
            const float p1 = K10 * pxv + K11 * pyv + K12 * pzv;
            const float d  = K20 * pxv + K21 * pyv + K22 * pzv;
            const float dpe = d + 1e-8f;
            const float u01 = p0 / dpe / 512.0f;
            const float v01 = p1 / dpe / 256.0f;
            const float vf = (u01 >= 0.0f && u01 <= 1.0f &&
                              v01 >= 0.0f && v01 <= 1.0f) ? 1.0f : 0.0f;

            float xp = u01 * 64.0f - 0.5f;
            xp = fminf(fmaxf(xp, -2.0f), 66.0f);
            const float x0f = floorf(xp);
            const float wx = xp - x0f;
            const int x0 = (int)x0f, x1i = x0 + 1;
            const float wx0 = (1.0f - wx) * vf * ((x0  >= 0 && x0  < 64) ? 1.0f : 0.0f);
            const float wx1 = wx          * vf * ((x1i >= 0 && x1i < 64) ? 1.0f : 0.0f);
            const int xi0 = min(max(x0, 0), 63);
            const int xi1 = min(max(x1i, 0), 63);

            float yp = v01 * 32.0f - 0.5f;
            yp = fminf(fmaxf(yp, -2.0f), 34.0f);
            const float y0f = floorf(yp);
            const float wy = yp - y0f;
            const int y0 = (int)y0f, y1i = y0 + 1;
            const float wy0 = (1.0f - wy) * ((y0  >= 0 && y0  < 32) ? 1.0f : 0.0f);
            const float wy1 = wy          * ((y1i >= 0 && y1i < 32) ? 1.0f : 0.0f);
            const int yi0 = min(max(y0, 0), 31);
            const int yi1 = min(max(y1i, 0), 31);

            wtsL[p]  = make_float4(wx0 * wy0, wx1 * wy0, wx0 * wy1, wx1 * wy1);
            offsL[p] = make_int4(((yi0 << 6) + xi0) << 3, ((yi0 << 6) + xi1) << 3,
                                 ((yi1 << 6) + xi0) << 3, ((yi1 << 6) + xi1) << 3);
        }
    }

    __syncthreads();

    // ---------- phase B: sample 64 channels per (n,y), write F to LDS ----------
    {
        const uint4* imgTb = imgTq + b * 16384;
        const int g  = t >> 3;      // 32 groups
        const int li = t & 7;       // lane-in-group: channel block c = li*8..+7

        #pragma unroll 2
        for (int it = 0; it < 16; ++it) {
            const int p    = it * 32 + g;
            const int4   off = offsL[p];
            const float4 w   = wtsL[p];
            const int nloc = p >> 3;
            const int y    = p & 7;

            float ac[8];
            #pragma unroll
            for (int q = 0; q < 8; ++q) ac[q] = 0.0f;

            uint4 v;
            v = imgTb[off.x + li];
            ac[0] += w.x * lo16(v.x); ac[1] += w.x * hi16(v.x);
            ac[2] += w.x * lo16(v.y); ac[3] += w.x * hi16(v.y);
            ac[4] += w.x * lo16(v.z); ac[5] += w.x * hi16(v.z);
            ac[6] += w.x * lo16(v.w); ac[7] += w.x * hi16(v.w);
            v = imgTb[off.y + li];
            ac[0] += w.y * lo16(v.x); ac[1] += w.y * hi16(v.x);
            ac[2] += w.y * lo16(v.y); ac[3] += w.y * hi16(v.y);
            ac[4] += w.y * lo16(v.z); ac[5] += w.y * hi16(v.z);
            ac[6] += w.y * lo16(v.w); ac[7] += w.y * hi16(v.w);
            v = imgTb[off.z + li];
            ac[0] += w.z * lo16(v.x); ac[1] += w.z * hi16(v.x);
            ac[2] += w.z * lo16(v.y); ac[3] += w.z * hi16(v.y);
            ac[4] += w.z * lo16(v.z); ac[5] += w.z * hi16(v.z);
            ac[6] += w.z * lo16(v.w); ac[7] += w.z * hi16(v.w);
            v = imgTb[off.w + li];
            ac[0] += w.w * lo16(v.x); ac[1] += w.w * hi16(v.x);
            ac[2] += w.w * lo16(v.y); ac[3] += w.w * hi16(v.y);
            ac[4] += w.w * lo16(v.z); ac[5] += w.w * hi16(v.z);
            ac[6] += w.w * lo16(v.w); ac[7] += w.w * hi16(v.w);

            uint4 pk;
            pk.x = rne16(ac[0]) | (rne16(ac[1]) << 16);
            pk.y = rne16(ac[2]) | (rne16(ac[3]) << 16);
            pk.z = rne16(ac[4]) | (rne16(ac[5]) << 16);
            pk.w = rne16(ac[6]) | (rne16(ac[7]) << 16);

            // F row nloc, k'-uint4 col (y*8+li), XOR-swizzled by (nloc&7)
            FsU[nloc * 64 + ((y * 8 + li) ^ (nloc & 7))] = pk;
        }
    }

    __syncthreads();

    // ---------- phase C: MFMA GEMM out[o][n] = sum_k Wp[o][k]*F[n][k] + bias ----------
    {
        const int wv  = t >> 6;     // wave 0..3 -> o rows wv*32..+31
        const int ln  = t & 63;
        const int l15 = ln & 15;
        const int lg  = ln >> 4;    // k-slot group

        const bf16x8* ApG = (const bf16x8*)Wp;      // [128 rows][64 slots]
        const bf16x8* Ap0 = ApG + ((wv * 32 +      l15) * 64 + lg);
        const bf16x8* Ap1 = ApG + ((wv * 32 + 16 + l15) * 64 + lg);
        const bf16x8* FsV = (const bf16x8*)FsU;

        f32x4 acc[2][4];
        #pragma unroll
        for (int h = 0; h < 2; ++h)
            #pragma unroll
            for (int nt = 0; nt < 4; ++nt)
                acc[h][nt] = (f32x4){0.0f, 0.0f, 0.0f, 0.0f};

        #pragma unroll 2
        for (int ks = 0; ks < 16; ++ks) {
            const bf16x8 a0 = Ap0[ks * 4];
            const bf16x8 a1 = Ap1[ks * 4];
            const int kq = ks * 4 + lg;
            #pragma unroll
            for (int nt = 0; nt < 4; ++nt) {
                const int nn = nt * 16 + l15;
                const bf16x8 bf = FsV[nn * 64 + (kq ^ (nn & 7))];
                acc[0][nt] = __builtin_amdgcn_mfma_f32_16x16x32_bf16(a0, bf, acc[0][nt], 0, 0, 0);
                acc[1][nt] = __builtin_amdgcn_mfma_f32_16x16x32_bf16(a1, bf, acc[1][nt], 0, 0, 0);
            }
        }

        float bias_[2][4];
        #pragma unroll
        for (int h = 0; h < 2; ++h)
            #pragma unroll
            for (int r = 0; r < 4; ++r)
                bias_[h][r] = convb[wv * 32 + h * 16 + lg * 4 + r];

        float* ob = out + (size_t)(b * 128 + wv * 32) * NPOS + n0;
        #pragma unroll
        for (int h = 0; h < 2; ++h)
            #pragma unroll
            for (int nt = 0; nt < 4; ++nt)
                #pragma unroll
                for (int r = 0; r < 4; ++r)
                    ob[(h * 16 + lg * 4 + r) * NPOS + nt * 16 + l15] =
                        acc[h][nt][r] + bias_[h][r];
    }
}

extern "C" void kernel_launch(void* const* d_in, const int* in_sizes, int n_in,
                              void* d_out, int out_size, void* d_ws, size_t ws_size,
                              hipStream_t stream) {
    const float* img   = (const float*)d_in[0];
    const float* pixT  = (const float*)d_in[1];
    const float* convw = (const float*)d_in[2];
    const float* convb = (const float*)d_in[3];
    float* out = (float*)d_out;

    unsigned short* imgT = (unsigned short*)d_ws;             // 262144 bf16 = 512 KiB
    unsigned short* Wp   = imgT + 262144;                     // 65536 bf16 = 128 KiB

    hipLaunchKernelGGL(bili_prep, dim3(1280), dim3(256), 0, stream,
                       img, convw, imgT, Wp);
    hipLaunchKernelGGL(bili_main, dim3(625, 2), dim3(256), 0, stream,
                       (const uint4*)imgT, Wp, pixT, convb, out);
}